// Round 2
// baseline (572.837 us; speedup 1.0000x reference)
//
#include <hip/hip_runtime.h>
#include <stdint.h>

#define B_     128
#define T_     64
#define HW_    2048
#define N_     131072
#define NB_    16384      /* N_/8 bytes of src bitmask per row */
#define BINS1  8192
#define SHIFT1 19
#define SUBSHIFT 6
#define SUBBINS  8192
#define BANDW  256u
#define CAP    4096
#define FULLG  (B_ * 64)  /* 8192 blocks: 64 slots/row, 2048 elems/slot */

// ---------- helpers ----------

__device__ __forceinline__ uint32_t fkey(float p) {
  uint32_t u = __float_as_uint(p);
  return u ^ ((u & 0x80000000u) ? 0xFFFFFFFFu : 0x80000000u);
}

// fast natural log: hardware v_log_f32 (log2) * ln2. deterministic, no contract.
__device__ __forceinline__ float fastln(float x) {
  #pragma clang fp contract(off)
  float l2 = __log2f(x);
  return l2 * 0.6931471805599453f;
}

// exact: correctly-rounded f32 natural log via double
__device__ __forceinline__ float exactln(float x) {
  return (float)log((double)x);
}

// ---------- LUT: per (b,t) constants, exact f32 semantics ----------
__global__ void lut_kernel(const float* __restrict__ Uts, const float* __restrict__ Utt,
                           float* c1src, float* c1tgt, float* cpref) {
  #pragma clang fp contract(off)
  int b = blockIdx.x, t = threadIdx.x;
  c1src[b * T_ + t] = exactln(Uts[b * T_ + t]) * 0.5f;
  c1tgt[b * T_ + t] = exactln(Utt[b * T_ + t]) * 0.5f;
  if (b == 0) {
    const double st = (0.001 - 1.0) / 63.0;   // numpy linspace step (f64)
    double a = (double)t * st;
    double y = a + 1.0;
    if (t == 63) y = 0.001;                   // numpy endpoint fixup
    float L = (float)y;
    float ex = (float)(1.0 / 3.0);
    float pf = (float)pow((double)L, (double)ex);
    if (pf < 1e-9f) pf = 1e-9f;
    cpref[t] = exactln(pf);
    if (t == 0) cpref[64] = exactln(1e-9f);
  }
}

// ---------- A: 13-bit histogram of fast keys ----------
template <bool TGT>
__global__ __launch_bounds__(256) void histA(const float* __restrict__ U0,
                                             const float* __restrict__ c1lut,
                                             const float* __restrict__ cpref,
                                             const uint8_t* __restrict__ bits,
                                             uint32_t* __restrict__ hist1) {
  #pragma clang fp contract(off)
  __shared__ uint32_t lh[BINS1];
  for (int i = threadIdx.x; i < BINS1; i += 256) lh[i] = 0;
  __syncthreads();
  int row = blockIdx.x >> 6, slot = blockIdx.x & 63;
  int n0 = slot * HW_ + threadIdx.x * 8;
  const float4* p = (const float4*)(U0 + (size_t)row * N_ + n0);
  float4 va = p[0], vb = p[1];
  float u[8] = {va.x, va.y, va.z, va.w, vb.x, vb.y, vb.z, vb.w};
  float c1 = c1lut[row * T_ + slot];
  float c2s = cpref[slot];
  float lc9 = cpref[64];
  uint8_t byte = TGT ? bits[(size_t)row * NB_ + (n0 >> 3)] : (uint8_t)0;
  #pragma unroll
  for (int j = 0; j < 8; j++) {
    float c2 = TGT ? ((((byte >> j) & 1) != 0) ? lc9 : 0.0f) : c2s;
    float P = (fastln(u[j]) + c1) + c2;
    atomicAdd(&lh[fkey(P) >> SHIFT1], 1u);
  }
  __syncthreads();
  uint32_t* gh = hist1 + (size_t)row * BINS1;
  for (int i = threadIdx.x; i < BINS1; i += 256)
    if (lh[i]) atomicAdd(&gh[i], lh[i]);
}

// ---------- descending-rank bin pick (shared by B1/B2) ----------
__device__ void pick_desc(const uint32_t* h, uint32_t K, uint32_t* sh,
                          uint32_t* bin_out, uint32_t* cum_out) {
  const int CH = BINS1 / 256;
  uint32_t s = 0;
  int c0 = threadIdx.x * CH;
  for (int i = 0; i < CH; i++) s += h[c0 + i];
  sh[threadIdx.x] = s;
  __syncthreads();
  if (threadIdx.x == 0) {
    uint32_t cum = 0, bin = 0, ca = 0;
    for (int c = 255; c >= 0; c--) {
      if (cum + sh[c] >= K) {
        uint32_t cc = cum;
        for (int b0 = c * CH + CH - 1; b0 >= c * CH; b0--) {
          uint32_t hv = h[b0];
          if (cc + hv >= K) { bin = (uint32_t)b0; ca = cc; break; }
          cc += hv;
        }
        break;
      }
      cum += sh[c];
    }
    *bin_out = bin; *cum_out = ca;
  }
}

__global__ void pickbin1(const uint32_t* __restrict__ hist1, const int* __restrict__ pK,
                         uint32_t* lo1, uint32_t* cumA) {
  __shared__ uint32_t sh[256];
  __shared__ uint32_t rbin, rcum;
  int row = blockIdx.x;
  pick_desc(hist1 + (size_t)row * BINS1, (uint32_t)*pK, sh, &rbin, &rcum);
  __syncthreads();
  if (threadIdx.x == 0) { lo1[row] = rbin << SHIFT1; cumA[row] = rcum; }
}

// ---------- C: 6-bit sub-histogram within bin1 ----------
template <bool TGT>
__global__ __launch_bounds__(256) void histC(const float* __restrict__ U0,
                                             const float* __restrict__ c1lut,
                                             const float* __restrict__ cpref,
                                             const uint8_t* __restrict__ bits,
                                             const uint32_t* __restrict__ lo1v,
                                             uint32_t* __restrict__ hist2) {
  #pragma clang fp contract(off)
  __shared__ uint32_t lh[SUBBINS];
  for (int i = threadIdx.x; i < SUBBINS; i += 256) lh[i] = 0;
  __syncthreads();
  int row = blockIdx.x >> 6, slot = blockIdx.x & 63;
  int n0 = slot * HW_ + threadIdx.x * 8;
  uint32_t lo1 = lo1v[row];
  const float4* p = (const float4*)(U0 + (size_t)row * N_ + n0);
  float4 va = p[0], vb = p[1];
  float u[8] = {va.x, va.y, va.z, va.w, vb.x, vb.y, vb.z, vb.w};
  float c1 = c1lut[row * T_ + slot];
  float c2s = cpref[slot];
  float lc9 = cpref[64];
  uint8_t byte = TGT ? bits[(size_t)row * NB_ + (n0 >> 3)] : (uint8_t)0;
  #pragma unroll
  for (int j = 0; j < 8; j++) {
    float c2 = TGT ? ((((byte >> j) & 1) != 0) ? lc9 : 0.0f) : c2s;
    float P = (fastln(u[j]) + c1) + c2;
    uint32_t k = fkey(P);
    if (k >= lo1 && (k - lo1) < (1u << SHIFT1))
      atomicAdd(&lh[(k - lo1) >> SUBSHIFT], 1u);
  }
  __syncthreads();
  uint32_t* gh = hist2 + (size_t)row * SUBBINS;
  for (int i = threadIdx.x; i < SUBBINS; i += 256)
    if (lh[i]) atomicAdd(&gh[i], lh[i]);
}

__global__ void pickbin2(const uint32_t* __restrict__ hist2, const int* __restrict__ pK,
                         const uint32_t* __restrict__ lo1v, const uint32_t* __restrict__ cumA,
                         uint32_t* lo2v) {
  __shared__ uint32_t sh[256];
  __shared__ uint32_t rbin, rcum;
  int row = blockIdx.x;
  uint32_t K2 = (uint32_t)*pK - cumA[row];   // rank within bin1; >=1 by construction
  pick_desc(hist2 + (size_t)row * SUBBINS, K2, sh, &rbin, &rcum);
  __syncthreads();
  if (threadIdx.x == 0) lo2v[row] = lo1v[row] + (rbin << SUBSHIFT);
}

// ---------- D: write mask (int32 0/1) for out-of-band, gather band, count above ----------
template <bool TGT>
__global__ __launch_bounds__(256) void maskD(const float* __restrict__ U0,
                                             const float* __restrict__ c1lut,
                                             const float* __restrict__ cpref,
                                             const uint8_t* __restrict__ bits_in,
                                             const uint32_t* __restrict__ lo2v,
                                             int* __restrict__ out,
                                             uint8_t* __restrict__ bits_out,
                                             uint32_t* __restrict__ bandcnt,
                                             uint32_t* __restrict__ cntabove,
                                             uint32_t* __restrict__ bandidx) {
  #pragma clang fp contract(off)
  __shared__ uint32_t blk;
  if (threadIdx.x == 0) blk = 0;
  __syncthreads();
  int row = blockIdx.x >> 6, slot = blockIdx.x & 63;
  int n0 = slot * HW_ + threadIdx.x * 8;
  uint32_t lo2 = lo2v[row];
  uint32_t blo = (lo2 >= BANDW) ? lo2 - BANDW : 0u;
  uint32_t bhi = lo2 + ((1u << SUBSHIFT) - 1u) + BANDW;
  const float4* p = (const float4*)(U0 + (size_t)row * N_ + n0);
  float4 va = p[0], vb = p[1];
  float u[8] = {va.x, va.y, va.z, va.w, vb.x, vb.y, vb.z, vb.w};
  float c1 = c1lut[row * T_ + slot];
  float c2s = cpref[slot];
  float lc9 = cpref[64];
  uint8_t byte = TGT ? bits_in[(size_t)row * NB_ + (n0 >> 3)] : (uint8_t)0;
  int ov[8];
  uint32_t above = 0;
  uint8_t ob = 0;
  #pragma unroll
  for (int j = 0; j < 8; j++) {
    float c2 = TGT ? ((((byte >> j) & 1) != 0) ? lc9 : 0.0f) : c2s;
    float P = (fastln(u[j]) + c1) + c2;
    uint32_t k = fkey(P);
    if (k > bhi) {
      ov[j] = 1; above++; ob |= (uint8_t)(1u << j);
    } else {
      ov[j] = 0;
      if (k >= blo) {
        uint32_t pos = atomicAdd(&bandcnt[row], 1u);
        if (pos < CAP) bandidx[(size_t)row * CAP + pos] = (uint32_t)(n0 + j);
      }
    }
  }
  int4 o0 = {ov[0], ov[1], ov[2], ov[3]};
  int4 o1 = {ov[4], ov[5], ov[6], ov[7]};
  int4* q = (int4*)(out + (size_t)row * N_ + n0);
  q[0] = o0; q[1] = o1;
  if (!TGT) bits_out[(size_t)row * NB_ + (n0 >> 3)] = ob;
  if (above) atomicAdd(&blk, above);
  __syncthreads();
  if (threadIdx.x == 0 && blk) atomicAdd(&cntabove[row], blk);
}

// ---------- E: exact resolve of the band (correctly-rounded logs, stable ties) ----------
template <bool TGT>
__global__ __launch_bounds__(256) void resolveE(const float* __restrict__ U0,
                                                const float* __restrict__ c1lut,
                                                const float* __restrict__ cpref,
                                                const uint8_t* __restrict__ bits_in,
                                                const int* __restrict__ pK,
                                                const uint32_t* __restrict__ bandcnt,
                                                const uint32_t* __restrict__ cntabove,
                                                const uint32_t* __restrict__ bandidx,
                                                int* __restrict__ out,
                                                uint8_t* __restrict__ bits_out) {
  #pragma clang fp contract(off)
  __shared__ uint32_t keys[CAP];
  __shared__ uint32_t inds[CAP];
  int row = blockIdx.x;
  uint32_t cnt = bandcnt[row];
  if (cnt > CAP) cnt = CAP;
  uint32_t K = (uint32_t)*pK;
  uint32_t ca = cntabove[row];
  uint32_t R = (K > ca) ? (K - ca) : 0u;   // slots to fill from band
  float lc9 = cpref[64];
  for (uint32_t i = threadIdx.x; i < cnt; i += 256) {
    uint32_t idx = bandidx[(size_t)row * CAP + i];
    float u0v = U0[(size_t)row * N_ + idx];
    uint32_t t = idx >> 11;
    float lu0 = exactln(u0v);
    float c2;
    if (TGT) {
      uint8_t bt = bits_in[(size_t)row * NB_ + (idx >> 3)];
      c2 = (((bt >> (idx & 7)) & 1) != 0) ? lc9 : 0.0f;
    } else {
      c2 = cpref[t];
    }
    float P = (lu0 + c1lut[row * T_ + t]) + c2;
    keys[i] = fkey(P);
    inds[i] = idx;
  }
  __syncthreads();
  for (uint32_t i = threadIdx.x; i < cnt; i += 256) {
    uint32_t k = keys[i], id = inds[i], r = 0;
    for (uint32_t j = 0; j < cnt; j++) {
      uint32_t kj = keys[j];
      r += (uint32_t)((kj > k) || (kj == k && inds[j] < id));
    }
    if (r < R) {
      out[(size_t)row * N_ + id] = 1;
      if (!TGT)
        atomicOr((uint32_t*)(bits_out + (size_t)row * NB_) + (id >> 5), 1u << (id & 31));
    }
  }
}

// ---------- launch ----------
extern "C" void kernel_launch(void* const* d_in, const int* in_sizes, int n_in,
                              void* d_out, int out_size, void* d_ws, size_t ws_size,
                              hipStream_t stream) {
  const float* U0s = (const float*)d_in[0];
  const float* Uts = (const float*)d_in[1];
  const float* U0t = (const float*)d_in[2];
  const float* Utt = (const float*)d_in[3];
  const int* Ks = (const int*)d_in[4];
  const int* Kt = (const int*)d_in[5];
  int* out = (int*)d_out;
  char* ws = (char*)d_ws;

  // ws layout (bytes)
  uint32_t* hist1   = (uint32_t*)(ws + 0);          // 4 MiB
  uint32_t* hist2   = (uint32_t*)(ws + 4194304);    // 4 MiB
  uint32_t* bandcnt = (uint32_t*)(ws + 8388608);    // 512
  uint32_t* cntabv  = (uint32_t*)(ws + 8389120);    // 512
  uint32_t* lo1     = (uint32_t*)(ws + 8389632);    // 512
  uint32_t* cumA    = (uint32_t*)(ws + 8390144);    // 512
  uint32_t* lo2     = (uint32_t*)(ws + 8390656);    // 512
  float*    c1src   = (float*)(ws + 8391168);       // 32 KiB
  float*    c1tgt   = (float*)(ws + 8423936);       // 32 KiB
  float*    cpref   = (float*)(ws + 8456704);       // 512 B (65 used)
  uint32_t* bandidx = (uint32_t*)(ws + 8457216);    // 2 MiB
  uint8_t*  bits    = (uint8_t*)(ws + 10554368);    // 2 MiB  (ends ~12.1 MiB)

  lut_kernel<<<B_, T_, 0, stream>>>(Uts, Utt, c1src, c1tgt, cpref);

  // ---- SRC mask -> out[0 .. B*N) ----
  hipMemsetAsync(ws, 0, 8389632, stream);  // hist1+hist2+bandcnt+cntabove
  histA<false><<<FULLG, 256, 0, stream>>>(U0s, c1src, cpref, nullptr, hist1);
  pickbin1<<<B_, 256, 0, stream>>>(hist1, Ks, lo1, cumA);
  histC<false><<<FULLG, 256, 0, stream>>>(U0s, c1src, cpref, nullptr, lo1, hist2);
  pickbin2<<<B_, 256, 0, stream>>>(hist2, Ks, lo1, cumA, lo2);
  maskD<false><<<FULLG, 256, 0, stream>>>(U0s, c1src, cpref, nullptr, lo2,
                                          out, bits, bandcnt, cntabv, bandidx);
  resolveE<false><<<B_, 256, 0, stream>>>(U0s, c1src, cpref, nullptr, Ks,
                                          bandcnt, cntabv, bandidx, out, bits);

  // ---- TGT mask (conditioned on src bits) -> out[B*N .. 2*B*N) ----
  int* out2 = out + (size_t)B_ * N_;
  hipMemsetAsync(ws, 0, 8389632, stream);
  histA<true><<<FULLG, 256, 0, stream>>>(U0t, c1tgt, cpref, bits, hist1);
  pickbin1<<<B_, 256, 0, stream>>>(hist1, Kt, lo1, cumA);
  histC<true><<<FULLG, 256, 0, stream>>>(U0t, c1tgt, cpref, bits, lo1, hist2);
  pickbin2<<<B_, 256, 0, stream>>>(hist2, Kt, lo1, cumA, lo2);
  maskD<true><<<FULLG, 256, 0, stream>>>(U0t, c1tgt, cpref, bits, lo2,
                                         out2, nullptr, bandcnt, cntabv, bandidx);
  resolveE<true><<<B_, 256, 0, stream>>>(U0t, c1tgt, cpref, bits, Kt,
                                         bandcnt, cntabv, bandidx, out2, nullptr);
}